// Round 1
// baseline (15144.533 us; speedup 1.0000x reference)
//
#include <hip/hip_runtime.h>

#define HDIM 128
#define TTOK 8
#define NPG 1024

// ---------------- scatter: agg[dst[e]] += x[src[e]] (32 threads/edge, float4) ----------------
__global__ __launch_bounds__(256) void scatter_kernel(const float* __restrict__ x,
    const int* __restrict__ src, const int* __restrict__ dst,
    float* __restrict__ agg, int E)
{
    int gt = blockIdx.x * 256 + threadIdx.x;
    int e = gt >> 5;
    if (e >= E) return;
    int lane = gt & 31;
    int s = src[e], d = dst[e];
    float4 v = *(const float4*)(x + (size_t)s * HDIM + lane * 4);
    float* ap = agg + (size_t)d * HDIM + lane * 4;
    atomicAdd(ap + 0, v.x);
    atomicAdd(ap + 1, v.y);
    atomicAdd(ap + 2, v.z);
    atomicAdd(ap + 3, v.w);
}

// ---------------- Y = (X1 [+ X2]) @ W + b ; W is 128x128 row-major ----------------
// 256 threads, 32 rows per block, 4x4 register micro-tile per thread.
__global__ __launch_bounds__(256) void lin128_kernel(const float* __restrict__ X1,
    const float* __restrict__ X2, const float* __restrict__ W,
    const float* __restrict__ bias, float* __restrict__ Y, int nrows)
{
    __shared__ float Wl[128 * 128];
    __shared__ float xr[32][128];
    int tid = threadIdx.x;
    for (int i = tid; i < 128 * 128; i += 256) Wl[i] = W[i];
    size_t r0 = (size_t)blockIdx.x * 32;
    for (int i = tid; i < 32 * 32; i += 256) {
        int r = i >> 5, c4 = i & 31;
        float4 v = *(const float4*)(X1 + (r0 + r) * HDIM + c4 * 4);
        if (X2) {
            float4 u = *(const float4*)(X2 + (r0 + r) * HDIM + c4 * 4);
            v.x += u.x; v.y += u.y; v.z += u.z; v.w += u.w;
        }
        *(float4*)&xr[r][c4 * 4] = v;
    }
    __syncthreads();
    int cg = tid & 31, rg = tid >> 5;
    int c0 = cg * 4, rb = rg * 4;
    float4 bv = *(const float4*)(bias + c0);
    float4 a0 = bv, a1 = bv, a2 = bv, a3 = bv;
    for (int k = 0; k < 128; ++k) {
        float4 w = *(const float4*)&Wl[k * 128 + c0];
        float x0 = xr[rb + 0][k], x1 = xr[rb + 1][k], x2 = xr[rb + 2][k], x3 = xr[rb + 3][k];
        a0.x += x0 * w.x; a0.y += x0 * w.y; a0.z += x0 * w.z; a0.w += x0 * w.w;
        a1.x += x1 * w.x; a1.y += x1 * w.y; a1.z += x1 * w.z; a1.w += x1 * w.w;
        a2.x += x2 * w.x; a2.y += x2 * w.y; a2.z += x2 * w.z; a2.w += x2 * w.w;
        a3.x += x3 * w.x; a3.y += x3 * w.y; a3.z += x3 * w.z; a3.w += x3 * w.w;
    }
    *(float4*)(Y + (r0 + rb + 0) * HDIM + c0) = a0;
    *(float4*)(Y + (r0 + rb + 1) * HDIM + c0) = a1;
    *(float4*)(Y + (r0 + rb + 2) * HDIM + c0) = a2;
    *(float4*)(Y + (r0 + rb + 3) * HDIM + c0) = a3;
}

// ---------------- attention prep: q = vt@Wq + bq ; P[h][t][:] = Wk_h @ q[t,h] / sqrt(32) ----------------
__global__ __launch_bounds__(256) void attn_prep_kernel(const float* __restrict__ vt,
    const float* __restrict__ qkv_w, const float* __restrict__ qkv_b, float* __restrict__ P)
{
    __shared__ float vtl[TTOK][HDIM];
    __shared__ float q[TTOK][HDIM];
    int tid = threadIdx.x;
    for (int i = tid; i < TTOK * HDIM; i += 256) vtl[i >> 7][i & 127] = vt[i];
    __syncthreads();
    for (int i = tid; i < TTOK * HDIM; i += 256) {
        int t = i >> 7, j = i & 127;
        float acc = qkv_b[j];
        for (int c = 0; c < 128; ++c) acc += vtl[t][c] * qkv_w[c * 384 + j];
        q[t][j] = acc;
    }
    __syncthreads();
    const float scale = 0.17677669529663687f; // 1/sqrt(32)
    for (int i = tid; i < 4 * TTOK * HDIM; i += 256) {
        int h = i >> 10, t = (i >> 7) & 7, cc = i & 127;
        float acc = 0.f;
        for (int d = 0; d < 32; ++d)
            acc += qkv_w[cc * 384 + 128 + h * 32 + d] * q[t][h * 32 + d];
        P[i] = acc * scale;
    }
}

// ---------------- fused attention per (graph, head): never materializes K/V ----------------
__global__ __launch_bounds__(256) void attn_main_kernel(const float* __restrict__ X,
    const float* __restrict__ P, const float* __restrict__ qkv_w,
    const float* __restrict__ qkv_b, float* __restrict__ O)
{
    __shared__ float sc[TTOK][NPG];   // 32 KB scores
    __shared__ float ph[TTOK][132];
    __shared__ float xt[32][132];
    __shared__ float rr[TTOK][HDIM];
    __shared__ float red[16];
    int b = blockIdx.x >> 2;
    int h = blockIdx.x & 3;
    int tid = threadIdx.x;
    for (int i = tid; i < TTOK * HDIM; i += 256) ph[i >> 7][i & 127] = P[h * 1024 + i];
    __syncthreads();
    const float* xg = X + (size_t)b * NPG * HDIM;
    // phase 1: scores
    for (int n0 = 0; n0 < NPG; n0 += 32) {
        for (int i = tid; i < 32 * 32; i += 256) {
            int n = i >> 5, c4 = i & 31;
            float4 v = *(const float4*)(xg + (size_t)(n0 + n) * HDIM + c4 * 4);
            *(float4*)&xt[n][c4 * 4] = v;
        }
        __syncthreads();
        int n = tid >> 3, t = tid & 7;
        float acc = 0.f;
        for (int k = 0; k < 128; k += 4) {
            float4 xv = *(const float4*)&xt[n][k];
            float4 pv = *(const float4*)&ph[t][k];
            acc += xv.x * pv.x + xv.y * pv.y + xv.z * pv.z + xv.w * pv.w;
        }
        sc[t][n0 + n] = acc;
        __syncthreads();
    }
    // softmax over n per token
    for (int t = 0; t < TTOK; ++t) {
        float m = -1e30f;
        for (int n = tid; n < NPG; n += 256) m = fmaxf(m, sc[t][n]);
        for (int off = 32; off; off >>= 1) m = fmaxf(m, __shfl_down(m, off));
        if ((tid & 63) == 0) red[tid >> 6] = m;
        __syncthreads();
        m = fmaxf(fmaxf(red[0], red[1]), fmaxf(red[2], red[3]));
        float s = 0.f;
        for (int n = tid; n < NPG; n += 256) {
            float e = __expf(sc[t][n] - m);
            sc[t][n] = e;
            s += e;
        }
        for (int off = 32; off; off >>= 1) s += __shfl_down(s, off);
        if ((tid & 63) == 0) red[4 + (tid >> 6)] = s;
        __syncthreads();
        s = red[4] + red[5] + red[6] + red[7];
        float inv = 1.f / s;
        for (int n = tid; n < NPG; n += 256) sc[t][n] *= inv;
        __syncthreads();
    }
    // phase 2: r[t][:] = sum_n a[t][n] * x_n
    {
        int t = tid >> 5, c4 = tid & 31;
        float4 acc = {0.f, 0.f, 0.f, 0.f};
        for (int n = 0; n < NPG; ++n) {
            float w = sc[t][n];
            float4 v = *(const float4*)(xg + (size_t)n * HDIM + c4 * 4);
            acc.x += w * v.x; acc.y += w * v.y; acc.z += w * v.z; acc.w += w * v.w;
        }
        *(float4*)&rr[t][c4 * 4] = acc;
    }
    __syncthreads();
    // epilogue: o[t][h*32+d] = r[t] @ Wv_h + bv
    {
        int t = tid >> 5, d = tid & 31;
        float acc = qkv_b[256 + h * 32 + d];
        for (int c = 0; c < 128; ++c)
            acc += rr[t][c] * qkv_w[c * 384 + 256 + h * 32 + d];
        O[((size_t)b * TTOK + t) * HDIM + h * 32 + d] = acc;
    }
}

// ---------------- mamba: one block per graph; writes GF[b][:] = mean_t output ----------------
__global__ __launch_bounds__(256) void mamba_kernel(const float* __restrict__ TOKp,
    const float* __restrict__ in_w, const float* __restrict__ conv_w,
    const float* __restrict__ conv_b, const float* __restrict__ x_w,
    const float* __restrict__ dt_w, const float* __restrict__ dt_b,
    const float* __restrict__ A_log, const float* __restrict__ Dp,
    const float* __restrict__ out_w, const float* __restrict__ norm_w,
    const float* __restrict__ normf_w, float* __restrict__ GF)
{
    constexpr int I = 256, S = 16;
    __shared__ float tok[TTOK][HDIM];
    __shared__ float hn[TTOK][HDIM];
    __shared__ float uu[TTOK][I];
    __shared__ float gg[TTOK][I];
    __shared__ float dtl[TTOK][I];
    __shared__ float ssm[TTOK][40];
    __shared__ float yy[TTOK][I];
    int b = blockIdx.x, tid = threadIdx.x;
    for (int i = tid; i < TTOK * HDIM; i += 256) tok[i >> 7][i & 127] = TOKp[(size_t)b * TTOK * HDIM + i];
    __syncthreads();
    // rmsnorm
    {
        int t = tid >> 5, lane = tid & 31;
        float s = 0.f;
        for (int c = lane; c < HDIM; c += 32) { float v = tok[t][c]; s += v * v; }
        for (int off = 16; off; off >>= 1) s += __shfl_down(s, off, 32);
        s = __shfl(s, 0, 32);
        float r = rsqrtf(s / HDIM + 1e-5f);
        for (int c = lane; c < HDIM; c += 32) hn[t][c] = tok[t][c] * r * norm_w[c];
    }
    __syncthreads();
    // proj = hn @ in_w  (128 x 512)
    for (int it = 0; it < 16; ++it) {
        int idx = it * 256 + tid;
        int t = idx >> 9, j = idx & 511;
        float acc = 0.f;
        for (int c = 0; c < 128; ++c) acc += hn[t][c] * in_w[c * 512 + j];
        if (j < 256) uu[t][j] = acc; else gg[t][j - 256] = acc;
    }
    __syncthreads();
    // causal depthwise conv (K=4) + silu, in place (descending t per channel, thread = i)
    {
        int i = tid;
        float cw0 = conv_w[i * 4 + 0], cw1 = conv_w[i * 4 + 1];
        float cw2 = conv_w[i * 4 + 2], cw3 = conv_w[i * 4 + 3];
        float cb = conv_b[i];
        float uv[TTOK];
        for (int t = 0; t < TTOK; ++t) uv[t] = uu[t][i];
        for (int t = 0; t < TTOK; ++t) {
            float a = cw3 * uv[t] + cb;
            if (t >= 1) a += cw2 * uv[t - 1];
            if (t >= 2) a += cw1 * uv[t - 2];
            if (t >= 3) a += cw0 * uv[t - 3];
            float sg = 1.f / (1.f + __expf(-a));
            uu[t][i] = a * sg;
        }
    }
    __syncthreads();
    // ssm = u @ x_w (256 x 40)
    for (int idx = tid; idx < TTOK * 40; idx += 256) {
        int t = idx / 40, j = idx % 40;
        float acc = 0.f;
        for (int c = 0; c < 256; ++c) acc += uu[t][c] * x_w[c * 40 + j];
        ssm[t][j] = acc;
    }
    __syncthreads();
    // dt = softplus(dtr @ dt_w + dt_b)
    for (int idx = tid; idx < TTOK * I; idx += 256) {
        int t = idx >> 8, i = idx & 255;
        float acc = dt_b[i];
        for (int r = 0; r < 8; ++r) acc += ssm[t][r] * dt_w[r * 256 + i];
        dtl[t][i] = (acc > 20.f) ? acc : log1pf(__expf(acc));
    }
    __syncthreads();
    // selective scan: thread = channel i, 16 states in registers
    {
        int i = tid;
        float a[S], st[S];
        for (int s = 0; s < S; ++s) { a[s] = -__expf(A_log[i * S + s]); st[s] = 0.f; }
        float Di = Dp[i];
        for (int t = 0; t < TTOK; ++t) {
            float d = dtl[t][i];
            float ut = uu[t][i];
            float y = 0.f;
            for (int s = 0; s < S; ++s) {
                float dA = __expf(d * a[s]);
                st[s] = dA * st[s] + d * ssm[t][8 + s] * ut;
                y += st[s] * ssm[t][24 + s];
            }
            y += ut * Di;
            float g = gg[t][i];
            float sg = 1.f / (1.f + __expf(-g));
            yy[t][i] = y * g * sg;
        }
    }
    __syncthreads();
    // out = yy @ out_w + residual -> hn
    for (int idx = tid; idx < TTOK * HDIM; idx += 256) {
        int t = idx >> 7, c = idx & 127;
        float acc = tok[t][c];
        for (int i = 0; i < 256; ++i) acc += yy[t][i] * out_w[i * 128 + c];
        hn[t][c] = acc;
    }
    __syncthreads();
    // final rmsnorm
    {
        int t = tid >> 5, lane = tid & 31;
        float s = 0.f;
        for (int c = lane; c < HDIM; c += 32) { float v = hn[t][c]; s += v * v; }
        for (int off = 16; off; off >>= 1) s += __shfl_down(s, off, 32);
        s = __shfl(s, 0, 32);
        float r = rsqrtf(s / HDIM + 1e-5f);
        for (int c = lane; c < HDIM; c += 32) hn[t][c] = hn[t][c] * r * normf_w[c];
    }
    __syncthreads();
    // GF[b][c] = mean over t
    for (int c = tid; c < HDIM; c += 256) {
        float s = 0.f;
        for (int t = 0; t < TTOK; ++t) s += hn[t][c];
        GF[(size_t)b * HDIM + c] = s * (1.f / TTOK);
    }
}

// ---------------- X = G + GF[batch] (batch = row >> 10) ----------------
__global__ __launch_bounds__(256) void add_gf_kernel(const float* __restrict__ G,
    const float* __restrict__ GF, float* __restrict__ Xo, int N)
{
    size_t idx = (size_t)blockIdx.x * 256 + threadIdx.x; // float4 index
    if (idx >= (size_t)N * 32) return;
    int c4 = idx & 31;
    size_t row = idx >> 5;
    int b = (int)(row >> 10);
    float4 g = *(const float4*)(G + idx * 4);
    float4 f = *(const float4*)(GF + (size_t)b * HDIM + c4 * 4);
    g.x += f.x; g.y += f.y; g.z += f.z; g.w += f.w;
    *(float4*)(Xo + idx * 4) = g;
}

// ---------------- fused final GIN + segment_sum: out[g] = (sum_i x+agg) @ W + 1024*b ----------------
__global__ __launch_bounds__(256) void final_kernel(const float* __restrict__ X,
    const float* __restrict__ A, const float* __restrict__ w_out,
    const float* __restrict__ b_out, float* __restrict__ out)
{
    __shared__ float Sm[HDIM];
    __shared__ float part[2][HDIM];
    int b = blockIdx.x, tid = threadIdx.x;
    int c = tid & 127, half = tid >> 7;
    float s = 0.f;
    for (int n = half; n < NPG; n += 2) {
        size_t idx = ((size_t)b * NPG + n) * HDIM + c;
        s += X[idx] + A[idx];
    }
    part[half][c] = s;
    __syncthreads();
    if (half == 0) Sm[c] = part[0][c] + part[1][c];
    __syncthreads();
    if (half == 0) {
        float acc = 1024.f * b_out[c];
        for (int k = 0; k < 128; ++k) acc += Sm[k] * w_out[k * 128 + c];
        out[(size_t)b * HDIM + c] = acc;
    }
}

extern "C" void kernel_launch(void* const* d_in, const int* in_sizes, int n_in,
                              void* d_out, int out_size, void* d_ws, size_t ws_size,
                              hipStream_t stream)
{
    const int N = in_sizes[0] / HDIM;      // 131072
    const int E = in_sizes[1] / 2;         // 2097152
    const int B = N >> 10;                 // 128 graphs

    const float* x_in  = (const float*)d_in[0];
    const int*   src   = (const int*)d_in[1];
    const int*   dst   = src + E;
    const float* w_in  = (const float*)d_in[5];
    const float* b_in  = (const float*)d_in[6];
    const float* gin_w = (const float*)d_in[7];
    const float* gin_b = (const float*)d_in[8];
    const float* vt    = (const float*)d_in[9];
    const float* qkv_w = (const float*)d_in[10];
    const float* qkv_b = (const float*)d_in[11];
    const float* ao_w  = (const float*)d_in[12];
    const float* ao_b  = (const float*)d_in[13];
    const float* m_in_w   = (const float*)d_in[14];
    const float* m_conv_w = (const float*)d_in[15];
    const float* m_conv_b = (const float*)d_in[16];
    const float* m_x_w    = (const float*)d_in[17];
    const float* m_dt_w   = (const float*)d_in[18];
    const float* m_dt_b   = (const float*)d_in[19];
    const float* m_A_log  = (const float*)d_in[20];
    const float* m_D      = (const float*)d_in[21];
    const float* m_out_w  = (const float*)d_in[22];
    const float* m_norm_w = (const float*)d_in[23];
    const float* m_normf_w= (const float*)d_in[24];
    const float* w_out = (const float*)d_in[25];
    const float* b_out = (const float*)d_in[26];
    float* out = (float*)d_out;

    float* X   = (float*)d_ws;
    float* A   = X + (size_t)N * HDIM;
    float* G   = A + (size_t)N * HDIM;
    float* TOK = G + (size_t)N * HDIM;
    float* O   = TOK + (size_t)B * TTOK * HDIM;
    float* GF  = O + (size_t)B * TTOK * HDIM;
    float* P   = GF + (size_t)B * HDIM;

    const size_t aggBytes = (size_t)N * HDIM * sizeof(float);
    const int scatterBlocks = (E * 32 + 255) / 256;

    // input GIN: X = (x + agg(x)) @ w_in + b_in
    hipMemsetAsync(A, 0, aggBytes, stream);
    scatter_kernel<<<scatterBlocks, 256, 0, stream>>>(x_in, src, dst, A, E);
    lin128_kernel<<<N / 32, 256, 0, stream>>>(x_in, A, w_in, b_in, X, N);

    for (int l = 0; l < 2; ++l) {
        // g = GIN(X)
        hipMemsetAsync(A, 0, aggBytes, stream);
        scatter_kernel<<<scatterBlocks, 256, 0, stream>>>(X, src, dst, A, E);
        lin128_kernel<<<N / 32, 256, 0, stream>>>(X, A, gin_w + (size_t)l * 128 * 128,
                                                  gin_b + (size_t)l * 128, G, N);
        // attention pool on X
        attn_prep_kernel<<<1, 256, 0, stream>>>(vt + (size_t)l * TTOK * HDIM,
                                                qkv_w + (size_t)l * 128 * 384,
                                                qkv_b + (size_t)l * 384, P);
        attn_main_kernel<<<B * 4, 256, 0, stream>>>(X, P,
                                                    qkv_w + (size_t)l * 128 * 384,
                                                    qkv_b + (size_t)l * 384, O);
        lin128_kernel<<<(B * TTOK) / 32, 256, 0, stream>>>(O, nullptr,
                                                           ao_w + (size_t)l * 128 * 128,
                                                           ao_b + (size_t)l * 128, TOK, B * TTOK);
        // mamba -> GF (mean over tokens)
        mamba_kernel<<<B, 256, 0, stream>>>(TOK, m_in_w, m_conv_w, m_conv_b, m_x_w,
                                            m_dt_w, m_dt_b, m_A_log, m_D, m_out_w,
                                            m_norm_w, m_normf_w, GF);
        // X = G + GF[batch]
        add_gf_kernel<<<(N * 32 + 255) / 256, 256, 0, stream>>>(G, GF, X, N);
    }

    // final GIN + segment_sum (fused via linearity)
    hipMemsetAsync(A, 0, aggBytes, stream);
    scatter_kernel<<<scatterBlocks, 256, 0, stream>>>(X, src, dst, A, E);
    final_kernel<<<B, 256, 0, stream>>>(X, A, w_out, b_out, out);

    (void)n_in; (void)out_size; (void)ws_size;
}

// Round 2
// 2830.741 us; speedup vs baseline: 5.3500x; 5.3500x over previous
//
#include <hip/hip_runtime.h>

#define HDIM 128
#define TTOK 8
#define NPG 1024

// ================= counting sort of edges by dst =================

__global__ __launch_bounds__(256) void hist_kernel(const int* __restrict__ dst,
                                                   int* __restrict__ count, int E)
{
    int e = blockIdx.x * 256 + threadIdx.x;
    if (e < E) atomicAdd(&count[dst[e]], 1);
}

__global__ __launch_bounds__(256) void reduce256_kernel(const int* __restrict__ count,
                                                        int* __restrict__ blocksum)
{
    __shared__ int sm[256];
    int tid = threadIdx.x;
    sm[tid] = count[blockIdx.x * 256 + tid];
    __syncthreads();
    for (int s = 128; s; s >>= 1) {
        if (tid < s) sm[tid] += sm[tid + s];
        __syncthreads();
    }
    if (tid == 0) blocksum[blockIdx.x] = sm[0];
}

__global__ __launch_bounds__(512) void scan512_kernel(const int* __restrict__ blocksum,
                                                      int* __restrict__ blockoff)
{
    __shared__ int tmp[512];
    int tid = threadIdx.x;
    int v = blocksum[tid];
    tmp[tid] = v;
    __syncthreads();
    for (int off = 1; off < 512; off <<= 1) {
        int t = (tid >= off) ? tmp[tid - off] : 0;
        __syncthreads();
        tmp[tid] += t;
        __syncthreads();
    }
    blockoff[tid] = tmp[tid] - v;  // exclusive
}

__global__ __launch_bounds__(256) void scan_local_kernel(const int* __restrict__ count,
    const int* __restrict__ blockoff, int* __restrict__ starts,
    int* __restrict__ cursor, int N)
{
    __shared__ int tmp[256];
    int tid = threadIdx.x;
    int i = blockIdx.x * 256 + tid;
    int v = count[i];
    tmp[tid] = v;
    __syncthreads();
    for (int off = 1; off < 256; off <<= 1) {
        int t = (tid >= off) ? tmp[tid - off] : 0;
        __syncthreads();
        tmp[tid] += t;
        __syncthreads();
    }
    int excl = tmp[tid] - v + blockoff[blockIdx.x];
    starts[i] = excl;
    cursor[i] = excl;
    if (i == N - 1) starts[N] = excl + v;  // == E
}

__global__ __launch_bounds__(256) void sort_scatter_kernel(const int* __restrict__ src,
    const int* __restrict__ dst, int* __restrict__ cursor,
    int* __restrict__ ssrc, int E)
{
    int e = blockIdx.x * 256 + threadIdx.x;
    if (e >= E) return;
    int pos = atomicAdd(&cursor[dst[e]], 1);
    ssrc[pos] = src[e];
}

// ================= gather-based segmented sum: A[n] = x[n] + sum_{e: dst=n} x[src[e]] =================
// 8 nodes per block, 32 lanes per node, float4 per lane (full 512B row per group-load).
__global__ __launch_bounds__(256) void gather_kernel(const float* __restrict__ X1,
    const int* __restrict__ ssrc, const int* __restrict__ starts,
    const int* __restrict__ count, float* __restrict__ A)
{
    int tid = threadIdx.x;
    int g = tid >> 5, lane = tid & 31;
    int node = blockIdx.x * 8 + g;
    const int c = lane * 4;
    float4 acc = *(const float4*)(X1 + (size_t)node * HDIM + c);
    int s0 = starts[node], cn = count[node];
    for (int j0 = 0; j0 < cn; j0 += 32) {
        int myid = (j0 + lane < cn) ? ssrc[s0 + j0 + lane] : 0;
        int m = min(32, cn - j0);
        int j = 0;
        for (; j + 1 < m; j += 2) {
            int sa = __shfl(myid, j, 32);
            int sb = __shfl(myid, j + 1, 32);
            float4 va = *(const float4*)(X1 + (size_t)sa * HDIM + c);
            float4 vb = *(const float4*)(X1 + (size_t)sb * HDIM + c);
            acc.x += va.x + vb.x; acc.y += va.y + vb.y;
            acc.z += va.z + vb.z; acc.w += va.w + vb.w;
        }
        if (j < m) {
            int sa = __shfl(myid, j, 32);
            float4 va = *(const float4*)(X1 + (size_t)sa * HDIM + c);
            acc.x += va.x; acc.y += va.y; acc.z += va.z; acc.w += va.w;
        }
    }
    *(float4*)(A + (size_t)node * HDIM + c) = acc;
}

// ================= Y = X1 @ W + b (in-place safe when Y==X1) =================
__global__ __launch_bounds__(256) void lin128_kernel(const float* __restrict__ X1,
    const float* __restrict__ W, const float* __restrict__ bias,
    float* __restrict__ Y)
{
    __shared__ float Wl[128 * 128];
    __shared__ float xr[32][128];
    int tid = threadIdx.x;
    for (int i = tid; i < 4096; i += 256)
        ((float4*)Wl)[i] = ((const float4*)W)[i];
    size_t r0 = (size_t)blockIdx.x * 32;
    for (int i = tid; i < 32 * 32; i += 256) {
        int r = i >> 5, c4 = i & 31;
        *(float4*)&xr[r][c4 * 4] = *(const float4*)(X1 + (r0 + r) * HDIM + c4 * 4);
    }
    __syncthreads();
    int cg = tid & 31, rg = tid >> 5;
    int c0 = cg * 4, rb = rg * 4;
    float4 bv = *(const float4*)(bias + c0);
    float4 a0 = bv, a1 = bv, a2 = bv, a3 = bv;
    for (int k = 0; k < 128; ++k) {
        float4 w = *(const float4*)&Wl[k * 128 + c0];
        float x0 = xr[rb + 0][k], x1 = xr[rb + 1][k], x2 = xr[rb + 2][k], x3 = xr[rb + 3][k];
        a0.x += x0 * w.x; a0.y += x0 * w.y; a0.z += x0 * w.z; a0.w += x0 * w.w;
        a1.x += x1 * w.x; a1.y += x1 * w.y; a1.z += x1 * w.z; a1.w += x1 * w.w;
        a2.x += x2 * w.x; a2.y += x2 * w.y; a2.z += x2 * w.z; a2.w += x2 * w.w;
        a3.x += x3 * w.x; a3.y += x3 * w.y; a3.z += x3 * w.z; a3.w += x3 * w.w;
    }
    *(float4*)(Y + (r0 + rb + 0) * HDIM + c0) = a0;
    *(float4*)(Y + (r0 + rb + 1) * HDIM + c0) = a1;
    *(float4*)(Y + (r0 + rb + 2) * HDIM + c0) = a2;
    *(float4*)(Y + (r0 + rb + 3) * HDIM + c0) = a3;
}

// ================= attention prep: P[h][t][:] = Wk_h @ q[t,h] / sqrt(32) =================
__global__ __launch_bounds__(256) void attn_prep_kernel(const float* __restrict__ vt,
    const float* __restrict__ qkv_w, const float* __restrict__ qkv_b, float* __restrict__ P)
{
    __shared__ float vtl[TTOK][HDIM];
    __shared__ float q[TTOK][HDIM];
    int tid = threadIdx.x;
    for (int i = tid; i < TTOK * HDIM; i += 256) vtl[i >> 7][i & 127] = vt[i];
    __syncthreads();
    for (int i = tid; i < TTOK * HDIM; i += 256) {
        int t = i >> 7, j = i & 127;
        float acc = qkv_b[j];
        for (int c = 0; c < 128; ++c) acc += vtl[t][c] * qkv_w[c * 384 + j];
        q[t][j] = acc;
    }
    __syncthreads();
    const float scale = 0.17677669529663687f; // 1/sqrt(32)
    for (int i = tid; i < 4 * TTOK * HDIM; i += 256) {
        int h = i >> 10, t = (i >> 7) & 7, cc = i & 127;
        float acc = 0.f;
        for (int d = 0; d < 32; ++d)
            acc += qkv_w[cc * 384 + 128 + h * 32 + d] * q[t][h * 32 + d];
        P[i] = acc * scale;
    }
}

// ================= fused attention per (graph, head): never materializes K/V =================
__global__ __launch_bounds__(256) void attn_main_kernel(const float* __restrict__ X,
    const float* __restrict__ P, const float* __restrict__ qkv_w,
    const float* __restrict__ qkv_b, float* __restrict__ O)
{
    __shared__ float sc[TTOK][NPG];   // 32 KB scores
    __shared__ float ph[TTOK][132];
    __shared__ float xt[32][132];
    __shared__ float rr[TTOK][HDIM];
    __shared__ float red[16];
    int b = blockIdx.x >> 2;
    int h = blockIdx.x & 3;
    int tid = threadIdx.x;
    for (int i = tid; i < TTOK * HDIM; i += 256) ph[i >> 7][i & 127] = P[h * 1024 + i];
    __syncthreads();
    const float* xg = X + (size_t)b * NPG * HDIM;
    for (int n0 = 0; n0 < NPG; n0 += 32) {
        for (int i = tid; i < 32 * 32; i += 256) {
            int n = i >> 5, c4 = i & 31;
            *(float4*)&xt[n][c4 * 4] = *(const float4*)(xg + (size_t)(n0 + n) * HDIM + c4 * 4);
        }
        __syncthreads();
        int n = tid >> 3, t = tid & 7;
        float acc = 0.f;
        for (int k = 0; k < 128; k += 4) {
            float4 xv = *(const float4*)&xt[n][k];
            float4 pv = *(const float4*)&ph[t][k];
            acc += xv.x * pv.x + xv.y * pv.y + xv.z * pv.z + xv.w * pv.w;
        }
        sc[t][n0 + n] = acc;
        __syncthreads();
    }
    for (int t = 0; t < TTOK; ++t) {
        float m = -1e30f;
        for (int n = tid; n < NPG; n += 256) m = fmaxf(m, sc[t][n]);
        for (int off = 32; off; off >>= 1) m = fmaxf(m, __shfl_down(m, off));
        if ((tid & 63) == 0) red[tid >> 6] = m;
        __syncthreads();
        m = fmaxf(fmaxf(red[0], red[1]), fmaxf(red[2], red[3]));
        float s = 0.f;
        for (int n = tid; n < NPG; n += 256) {
            float e = __expf(sc[t][n] - m);
            sc[t][n] = e;
            s += e;
        }
        for (int off = 32; off; off >>= 1) s += __shfl_down(s, off);
        if ((tid & 63) == 0) red[4 + (tid >> 6)] = s;
        __syncthreads();
        s = red[4] + red[5] + red[6] + red[7];
        float inv = 1.f / s;
        for (int n = tid; n < NPG; n += 256) sc[t][n] *= inv;
        __syncthreads();
    }
    {
        int t = tid >> 5, c4 = tid & 31;
        float4 acc = {0.f, 0.f, 0.f, 0.f};
        for (int n = 0; n < NPG; ++n) {
            float w = sc[t][n];
            float4 v = *(const float4*)(xg + (size_t)n * HDIM + c4 * 4);
            acc.x += w * v.x; acc.y += w * v.y; acc.z += w * v.z; acc.w += w * v.w;
        }
        *(float4*)&rr[t][c4 * 4] = acc;
    }
    __syncthreads();
    {
        int t = tid >> 5, d = tid & 31;
        float acc = qkv_b[256 + h * 32 + d];
        for (int c = 0; c < 128; ++c)
            acc += rr[t][c] * qkv_w[c * 384 + 256 + h * 32 + d];
        O[((size_t)b * TTOK + t) * HDIM + h * 32 + d] = acc;
    }
}

// ================= mamba: one block per graph; GF[b][:] = mean_t output =================
__global__ __launch_bounds__(256) void mamba_kernel(const float* __restrict__ TOKp,
    const float* __restrict__ in_w, const float* __restrict__ conv_w,
    const float* __restrict__ conv_b, const float* __restrict__ x_w,
    const float* __restrict__ dt_w, const float* __restrict__ dt_b,
    const float* __restrict__ A_log, const float* __restrict__ Dp,
    const float* __restrict__ out_w, const float* __restrict__ norm_w,
    const float* __restrict__ normf_w, float* __restrict__ GF)
{
    constexpr int I = 256, S = 16;
    __shared__ float tok[TTOK][HDIM];
    __shared__ float hn[TTOK][HDIM];
    __shared__ float uu[TTOK][I];
    __shared__ float gg[TTOK][I];
    __shared__ float dtl[TTOK][I];
    __shared__ float ssm[TTOK][40];
    __shared__ float yy[TTOK][I];
    int b = blockIdx.x, tid = threadIdx.x;
    for (int i = tid; i < TTOK * HDIM; i += 256) tok[i >> 7][i & 127] = TOKp[(size_t)b * TTOK * HDIM + i];
    __syncthreads();
    {
        int t = tid >> 5, lane = tid & 31;
        float s = 0.f;
        for (int c = lane; c < HDIM; c += 32) { float v = tok[t][c]; s += v * v; }
        for (int off = 16; off; off >>= 1) s += __shfl_down(s, off, 32);
        s = __shfl(s, 0, 32);
        float r = rsqrtf(s / HDIM + 1e-5f);
        for (int c = lane; c < HDIM; c += 32) hn[t][c] = tok[t][c] * r * norm_w[c];
    }
    __syncthreads();
    for (int it = 0; it < 16; ++it) {
        int idx = it * 256 + tid;
        int t = idx >> 9, j = idx & 511;
        float acc = 0.f;
        for (int c = 0; c < 128; ++c) acc += hn[t][c] * in_w[c * 512 + j];
        if (j < 256) uu[t][j] = acc; else gg[t][j - 256] = acc;
    }
    __syncthreads();
    {
        int i = tid;
        float cw0 = conv_w[i * 4 + 0], cw1 = conv_w[i * 4 + 1];
        float cw2 = conv_w[i * 4 + 2], cw3 = conv_w[i * 4 + 3];
        float cb = conv_b[i];
        float uv[TTOK];
        for (int t = 0; t < TTOK; ++t) uv[t] = uu[t][i];
        for (int t = 0; t < TTOK; ++t) {
            float a = cw3 * uv[t] + cb;
            if (t >= 1) a += cw2 * uv[t - 1];
            if (t >= 2) a += cw1 * uv[t - 2];
            if (t >= 3) a += cw0 * uv[t - 3];
            float sg = 1.f / (1.f + __expf(-a));
            uu[t][i] = a * sg;
        }
    }
    __syncthreads();
    for (int idx = tid; idx < TTOK * 40; idx += 256) {
        int t = idx / 40, j = idx % 40;
        float acc = 0.f;
        for (int c = 0; c < 256; ++c) acc += uu[t][c] * x_w[c * 40 + j];
        ssm[t][j] = acc;
    }
    __syncthreads();
    for (int idx = tid; idx < TTOK * I; idx += 256) {
        int t = idx >> 8, i = idx & 255;
        float acc = dt_b[i];
        for (int r = 0; r < 8; ++r) acc += ssm[t][r] * dt_w[r * 256 + i];
        dtl[t][i] = (acc > 20.f) ? acc : log1pf(__expf(acc));
    }
    __syncthreads();
    {
        int i = tid;
        float a[S], st[S];
        for (int s = 0; s < S; ++s) { a[s] = -__expf(A_log[i * S + s]); st[s] = 0.f; }
        float Di = Dp[i];
        for (int t = 0; t < TTOK; ++t) {
            float d = dtl[t][i];
            float ut = uu[t][i];
            float y = 0.f;
            for (int s = 0; s < S; ++s) {
                float dA = __expf(d * a[s]);
                st[s] = dA * st[s] + d * ssm[t][8 + s] * ut;
                y += st[s] * ssm[t][24 + s];
            }
            y += ut * Di;
            float g = gg[t][i];
            float sg = 1.f / (1.f + __expf(-g));
            yy[t][i] = y * g * sg;
        }
    }
    __syncthreads();
    for (int idx = tid; idx < TTOK * HDIM; idx += 256) {
        int t = idx >> 7, c = idx & 127;
        float acc = tok[t][c];
        for (int i = 0; i < 256; ++i) acc += yy[t][i] * out_w[i * 128 + c];
        hn[t][c] = acc;
    }
    __syncthreads();
    {
        int t = tid >> 5, lane = tid & 31;
        float s = 0.f;
        for (int c = lane; c < HDIM; c += 32) { float v = hn[t][c]; s += v * v; }
        for (int off = 16; off; off >>= 1) s += __shfl_down(s, off, 32);
        s = __shfl(s, 0, 32);
        float r = rsqrtf(s / HDIM + 1e-5f);
        for (int c = lane; c < HDIM; c += 32) hn[t][c] = hn[t][c] * r * normf_w[c];
    }
    __syncthreads();
    for (int c = tid; c < HDIM; c += 256) {
        float s = 0.f;
        for (int t = 0; t < TTOK; ++t) s += hn[t][c];
        GF[(size_t)b * HDIM + c] = s * (1.f / TTOK);
    }
}

// ================= X = G + GF[batch] =================
__global__ __launch_bounds__(256) void add_gf_kernel(const float* __restrict__ G,
    const float* __restrict__ GF, float* __restrict__ Xo, int N)
{
    size_t idx = (size_t)blockIdx.x * 256 + threadIdx.x; // float4 index
    if (idx >= (size_t)N * 32) return;
    int c4 = idx & 31;
    size_t row = idx >> 5;
    int b = (int)(row >> 10);
    float4 g = *(const float4*)(G + idx * 4);
    float4 f = *(const float4*)(GF + (size_t)b * HDIM + c4 * 4);
    g.x += f.x; g.y += f.y; g.z += f.z; g.w += f.w;
    *(float4*)(Xo + idx * 4) = g;
}

// ================= final GIN + segment_sum, gather-based =================
// out[g] = (sum_{n in g} X[n] + sum_{e: dst in g} X[src[e]]) @ W + 1024*b
__global__ __launch_bounds__(256) void final_kernel(const float* __restrict__ X,
    const int* __restrict__ ssrc, const int* __restrict__ starts,
    const float* __restrict__ w_out, const float* __restrict__ b_out,
    float* __restrict__ out)
{
    __shared__ float part[8][HDIM];
    __shared__ float Sm[HDIM];
    int b = blockIdx.x, tid = threadIdx.x;
    int g = tid >> 5, lane = tid & 31;
    const int c = lane * 4;
    float4 acc = {0.f, 0.f, 0.f, 0.f};
    // self rows
    for (int n = g; n < NPG; n += 8) {
        float4 v = *(const float4*)(X + ((size_t)b * NPG + n) * HDIM + c);
        acc.x += v.x; acc.y += v.y; acc.z += v.z; acc.w += v.w;
    }
    // edge rows (contiguous in dst-sorted order)
    int e0 = starts[b * NPG], e1 = starts[(b + 1) * NPG];
    for (int e = e0 + g; e < e1; e += 8) {
        int s = ssrc[e];
        float4 v = *(const float4*)(X + (size_t)s * HDIM + c);
        acc.x += v.x; acc.y += v.y; acc.z += v.z; acc.w += v.w;
    }
    *(float4*)&part[g][c] = acc;
    __syncthreads();
    if (tid < HDIM) {
        float s = 0.f;
        for (int gg = 0; gg < 8; ++gg) s += part[gg][tid];
        Sm[tid] = s;
    }
    __syncthreads();
    if (tid < HDIM) {
        float acc2 = 1024.f * b_out[tid];
        for (int k = 0; k < 128; ++k) acc2 += Sm[k] * w_out[k * 128 + tid];
        out[(size_t)b * HDIM + tid] = acc2;
    }
}

extern "C" void kernel_launch(void* const* d_in, const int* in_sizes, int n_in,
                              void* d_out, int out_size, void* d_ws, size_t ws_size,
                              hipStream_t stream)
{
    const int N = in_sizes[0] / HDIM;      // 131072
    const int E = in_sizes[1] / 2;         // 2097152
    const int B = N >> 10;                 // 128 graphs

    const float* x_in  = (const float*)d_in[0];
    const int*   src   = (const int*)d_in[1];
    const int*   dst   = src + E;
    const float* w_in  = (const float*)d_in[5];
    const float* b_in  = (const float*)d_in[6];
    const float* gin_w = (const float*)d_in[7];
    const float* gin_b = (const float*)d_in[8];
    const float* vt    = (const float*)d_in[9];
    const float* qkv_w = (const float*)d_in[10];
    const float* qkv_b = (const float*)d_in[11];
    const float* ao_w  = (const float*)d_in[12];
    const float* ao_b  = (const float*)d_in[13];
    const float* m_in_w   = (const float*)d_in[14];
    const float* m_conv_w = (const float*)d_in[15];
    const float* m_conv_b = (const float*)d_in[16];
    const float* m_x_w    = (const float*)d_in[17];
    const float* m_dt_w   = (const float*)d_in[18];
    const float* m_dt_b   = (const float*)d_in[19];
    const float* m_A_log  = (const float*)d_in[20];
    const float* m_D      = (const float*)d_in[21];
    const float* m_out_w  = (const float*)d_in[22];
    const float* m_norm_w = (const float*)d_in[23];
    const float* m_normf_w= (const float*)d_in[24];
    const float* w_out = (const float*)d_in[25];
    const float* b_out = (const float*)d_in[26];
    float* out = (float*)d_out;

    float* X   = (float*)d_ws;                    // N*128
    float* A   = X + (size_t)N * HDIM;            // N*128  (agg result, then in-place GIN output)
    float* TOK = A + (size_t)N * HDIM;            // B*8*128
    float* O   = TOK + (size_t)B * TTOK * HDIM;   // B*8*128
    float* GF  = O + (size_t)B * TTOK * HDIM;     // B*128
    float* P   = GF + (size_t)B * HDIM;           // 4*8*128
    int* count    = (int*)(P + 4 * TTOK * HDIM);  // N
    int* starts   = count + N;                    // N+1
    int* cursor   = starts + N + 1;               // N
    int* blocksum = cursor + N;                   // 512
    int* blockoff = blocksum + 512;               // 512
    int* ssrc     = blockoff + 512;               // E

    const int EB = (E + 255) / 256;   // 8192
    const int NB = N / 256;           // 512

    // ---- counting sort of edges by dst (once, reused by all 4 GINs) ----
    hipMemsetAsync(count, 0, (size_t)N * sizeof(int), stream);
    hist_kernel<<<EB, 256, 0, stream>>>(dst, count, E);
    reduce256_kernel<<<NB, 256, 0, stream>>>(count, blocksum);
    scan512_kernel<<<1, 512, 0, stream>>>(blocksum, blockoff);
    scan_local_kernel<<<NB, 256, 0, stream>>>(count, blockoff, starts, cursor, N);
    sort_scatter_kernel<<<EB, 256, 0, stream>>>(src, dst, cursor, ssrc, E);

    // ---- input GIN: X = (x + agg(x)) @ w_in + b_in ----
    gather_kernel<<<N / 8, 256, 0, stream>>>(x_in, ssrc, starts, count, A);
    lin128_kernel<<<N / 32, 256, 0, stream>>>(A, w_in, b_in, X);

    for (int l = 0; l < 2; ++l) {
        // g = GIN(X)  (gather into A, matmul in place)
        gather_kernel<<<N / 8, 256, 0, stream>>>(X, ssrc, starts, count, A);
        lin128_kernel<<<N / 32, 256, 0, stream>>>(A, gin_w + (size_t)l * 128 * 128,
                                                  gin_b + (size_t)l * 128, A);
        // attention pool on X
        attn_prep_kernel<<<1, 256, 0, stream>>>(vt + (size_t)l * TTOK * HDIM,
                                                qkv_w + (size_t)l * 128 * 384,
                                                qkv_b + (size_t)l * 384, P);
        attn_main_kernel<<<B * 4, 256, 0, stream>>>(X, P,
                                                    qkv_w + (size_t)l * 128 * 384,
                                                    qkv_b + (size_t)l * 384, O);
        lin128_kernel<<<(B * TTOK) / 32, 256, 0, stream>>>(O, ao_w + (size_t)l * 128 * 128,
                                                           ao_b + (size_t)l * 128, TOK);
        // mamba -> GF (mean over tokens)
        mamba_kernel<<<B, 256, 0, stream>>>(TOK, m_in_w, m_conv_w, m_conv_b, m_x_w,
                                            m_dt_w, m_dt_b, m_A_log, m_D, m_out_w,
                                            m_norm_w, m_normf_w, GF);
        // X = g + GF[batch]
        add_gf_kernel<<<(N * 32 + 255) / 256, 256, 0, stream>>>(A, GF, X, N);
    }

    // ---- final GIN + segment_sum (fused via linearity, gather-based) ----
    final_kernel<<<B, 256, 0, stream>>>(X, ssrc, starts, w_out, b_out, out);

    (void)n_in; (void)out_size; (void)ws_size;
}

// Round 3
// 1797.717 us; speedup vs baseline: 8.4243x; 1.5746x over previous
//
#include <hip/hip_runtime.h>

#define HDIM 128
#define TTOK 8
#define NPG 1024

// ================= counting sort of edges by dst =================

__global__ __launch_bounds__(256) void hist_kernel(const int* __restrict__ dst,
                                                   int* __restrict__ count, int E)
{
    int e = blockIdx.x * 256 + threadIdx.x;
    if (e < E) atomicAdd(&count[dst[e]], 1);
}

__global__ __launch_bounds__(256) void reduce256_kernel(const int* __restrict__ count,
                                                        int* __restrict__ blocksum)
{
    __shared__ int sm[256];
    int tid = threadIdx.x;
    sm[tid] = count[blockIdx.x * 256 + tid];
    __syncthreads();
    for (int s = 128; s; s >>= 1) {
        if (tid < s) sm[tid] += sm[tid + s];
        __syncthreads();
    }
    if (tid == 0) blocksum[blockIdx.x] = sm[0];
}

__global__ __launch_bounds__(512) void scan512_kernel(const int* __restrict__ blocksum,
                                                      int* __restrict__ blockoff)
{
    __shared__ int tmp[512];
    int tid = threadIdx.x;
    int v = blocksum[tid];
    tmp[tid] = v;
    __syncthreads();
    for (int off = 1; off < 512; off <<= 1) {
        int t = (tid >= off) ? tmp[tid - off] : 0;
        __syncthreads();
        tmp[tid] += t;
        __syncthreads();
    }
    blockoff[tid] = tmp[tid] - v;  // exclusive
}

__global__ __launch_bounds__(256) void scan_local_kernel(const int* __restrict__ count,
    const int* __restrict__ blockoff, int* __restrict__ starts,
    int* __restrict__ cursor, int N)
{
    __shared__ int tmp[256];
    int tid = threadIdx.x;
    int i = blockIdx.x * 256 + tid;
    int v = count[i];
    tmp[tid] = v;
    __syncthreads();
    for (int off = 1; off < 256; off <<= 1) {
        int t = (tid >= off) ? tmp[tid - off] : 0;
        __syncthreads();
        tmp[tid] += t;
        __syncthreads();
    }
    int excl = tmp[tid] - v + blockoff[blockIdx.x];
    starts[i] = excl;
    cursor[i] = excl;
    if (i == N - 1) starts[N] = excl + v;  // == E
}

__global__ __launch_bounds__(256) void sort_scatter_kernel(const int* __restrict__ src,
    const int* __restrict__ dst, int* __restrict__ cursor,
    int* __restrict__ ssrc, int E)
{
    int e = blockIdx.x * 256 + threadIdx.x;
    if (e >= E) return;
    int pos = atomicAdd(&cursor[dst[e]], 1);
    ssrc[pos] = src[e];
}

// ================= gather-based segmented sum: A[n] = x[n] + sum_{e: dst=n} x[src[e]] =================
__global__ __launch_bounds__(256) void gather_kernel(const float* __restrict__ X1,
    const int* __restrict__ ssrc, const int* __restrict__ starts,
    const int* __restrict__ count, float* __restrict__ A)
{
    int tid = threadIdx.x;
    int g = tid >> 5, lane = tid & 31;
    int node = blockIdx.x * 8 + g;
    const int c = lane * 4;
    float4 acc = *(const float4*)(X1 + (size_t)node * HDIM + c);
    int s0 = starts[node], cn = count[node];
    for (int j0 = 0; j0 < cn; j0 += 32) {
        int myid = (j0 + lane < cn) ? ssrc[s0 + j0 + lane] : 0;
        int m = min(32, cn - j0);
        int j = 0;
        for (; j + 1 < m; j += 2) {
            int sa = __shfl(myid, j, 32);
            int sb = __shfl(myid, j + 1, 32);
            float4 va = *(const float4*)(X1 + (size_t)sa * HDIM + c);
            float4 vb = *(const float4*)(X1 + (size_t)sb * HDIM + c);
            acc.x += va.x + vb.x; acc.y += va.y + vb.y;
            acc.z += va.z + vb.z; acc.w += va.w + vb.w;
        }
        if (j < m) {
            int sa = __shfl(myid, j, 32);
            float4 va = *(const float4*)(X1 + (size_t)sa * HDIM + c);
            acc.x += va.x; acc.y += va.y; acc.z += va.z; acc.w += va.w;
        }
    }
    *(float4*)(A + (size_t)node * HDIM + c) = acc;
}

// ================= Y = X1 @ W + b [+ GF[row>>10]] (in-place safe) =================
__global__ __launch_bounds__(256) void lin128_kernel(const float* __restrict__ X1,
    const float* __restrict__ W, const float* __restrict__ bias,
    const float* __restrict__ GF, float* __restrict__ Y)
{
    __shared__ float Wl[128 * 128];
    __shared__ float xr[32][128];
    int tid = threadIdx.x;
    for (int i = tid; i < 4096; i += 256)
        ((float4*)Wl)[i] = ((const float4*)W)[i];
    size_t r0 = (size_t)blockIdx.x * 32;
    for (int i = tid; i < 32 * 32; i += 256) {
        int r = i >> 5, c4 = i & 31;
        *(float4*)&xr[r][c4 * 4] = *(const float4*)(X1 + (r0 + r) * HDIM + c4 * 4);
    }
    __syncthreads();
    int cg = tid & 31, rg = tid >> 5;
    int c0 = cg * 4, rb = rg * 4;
    float4 bv = *(const float4*)(bias + c0);
    if (GF) {
        int b = (int)((r0 + rb) >> 10);  // 32-row block never crosses a 1024-row graph
        float4 gfv = *(const float4*)(GF + (size_t)b * HDIM + c0);
        bv.x += gfv.x; bv.y += gfv.y; bv.z += gfv.z; bv.w += gfv.w;
    }
    float4 a0 = bv, a1 = bv, a2 = bv, a3 = bv;
    for (int k = 0; k < 128; ++k) {
        float4 w = *(const float4*)&Wl[k * 128 + c0];
        float x0 = xr[rb + 0][k], x1 = xr[rb + 1][k], x2 = xr[rb + 2][k], x3 = xr[rb + 3][k];
        a0.x += x0 * w.x; a0.y += x0 * w.y; a0.z += x0 * w.z; a0.w += x0 * w.w;
        a1.x += x1 * w.x; a1.y += x1 * w.y; a1.z += x1 * w.z; a1.w += x1 * w.w;
        a2.x += x2 * w.x; a2.y += x2 * w.y; a2.z += x2 * w.z; a2.w += x2 * w.w;
        a3.x += x3 * w.x; a3.y += x3 * w.y; a3.z += x3 * w.z; a3.w += x3 * w.w;
    }
    *(float4*)(Y + (r0 + rb + 0) * HDIM + c0) = a0;
    *(float4*)(Y + (r0 + rb + 1) * HDIM + c0) = a1;
    *(float4*)(Y + (r0 + rb + 2) * HDIM + c0) = a2;
    *(float4*)(Y + (r0 + rb + 3) * HDIM + c0) = a3;
}

// ================= attention prep: P[h][t][:] = Wk_h @ q[t,h] / sqrt(32) =================
__global__ __launch_bounds__(256) void attn_prep_kernel(const float* __restrict__ vt,
    const float* __restrict__ qkv_w, const float* __restrict__ qkv_b, float* __restrict__ P)
{
    __shared__ float vtl[TTOK][HDIM];
    __shared__ float q[TTOK][HDIM];
    int tid = threadIdx.x;
    for (int i = tid; i < TTOK * HDIM; i += 256) vtl[i >> 7][i & 127] = vt[i];
    __syncthreads();
    for (int i = tid; i < TTOK * HDIM; i += 256) {
        int t = i >> 7, j = i & 127;
        float acc = qkv_b[j];
        for (int c = 0; c < 128; ++c) acc += vtl[t][c] * qkv_w[c * 384 + j];
        q[t][j] = acc;
    }
    __syncthreads();
    const float scale = 0.17677669529663687f; // 1/sqrt(32)
    for (int i = tid; i < 4 * TTOK * HDIM; i += 256) {
        int h = i >> 10, t = (i >> 7) & 7, cc = i & 127;
        float acc = 0.f;
        for (int d = 0; d < 32; ++d)
            acc += qkv_w[cc * 384 + 128 + h * 32 + d] * q[t][h * 32 + d];
        P[i] = acc * scale;
    }
}

// ================= fused attention per (graph, head) =================
__global__ __launch_bounds__(256) void attn_main_kernel(const float* __restrict__ X,
    const float* __restrict__ P, const float* __restrict__ qkv_w,
    const float* __restrict__ qkv_b, float* __restrict__ O)
{
    __shared__ float sc[TTOK][NPG];   // 32 KB scores
    __shared__ float ph[TTOK][132];
    __shared__ float xt[32][132];
    __shared__ float rr[TTOK][HDIM];
    __shared__ float red[16];
    int b = blockIdx.x >> 2;
    int h = blockIdx.x & 3;
    int tid = threadIdx.x;
    for (int i = tid; i < TTOK * HDIM; i += 256) ph[i >> 7][i & 127] = P[h * 1024 + i];
    __syncthreads();
    const float* xg = X + (size_t)b * NPG * HDIM;
    for (int n0 = 0; n0 < NPG; n0 += 32) {
        for (int i = tid; i < 32 * 32; i += 256) {
            int n = i >> 5, c4 = i & 31;
            *(float4*)&xt[n][c4 * 4] = *(const float4*)(xg + (size_t)(n0 + n) * HDIM + c4 * 4);
        }
        __syncthreads();
        int n = tid >> 3, t = tid & 7;
        float acc = 0.f;
        for (int k = 0; k < 128; k += 4) {
            float4 xv = *(const float4*)&xt[n][k];
            float4 pv = *(const float4*)&ph[t][k];
            acc += xv.x * pv.x + xv.y * pv.y + xv.z * pv.z + xv.w * pv.w;
        }
        sc[t][n0 + n] = acc;
        __syncthreads();
    }
    for (int t = 0; t < TTOK; ++t) {
        float m = -1e30f;
        for (int n = tid; n < NPG; n += 256) m = fmaxf(m, sc[t][n]);
        for (int off = 32; off; off >>= 1) m = fmaxf(m, __shfl_down(m, off));
        if ((tid & 63) == 0) red[tid >> 6] = m;
        __syncthreads();
        m = fmaxf(fmaxf(red[0], red[1]), fmaxf(red[2], red[3]));
        float s = 0.f;
        for (int n = tid; n < NPG; n += 256) {
            float e = __expf(sc[t][n] - m);
            sc[t][n] = e;
            s += e;
        }
        for (int off = 32; off; off >>= 1) s += __shfl_down(s, off);
        if ((tid & 63) == 0) red[4 + (tid >> 6)] = s;
        __syncthreads();
        s = red[4] + red[5] + red[6] + red[7];
        float inv = 1.f / s;
        for (int n = tid; n < NPG; n += 256) sc[t][n] *= inv;
        __syncthreads();
    }
    {
        int t = tid >> 5, c4 = tid & 31;
        float4 acc = {0.f, 0.f, 0.f, 0.f};
        for (int n = 0; n < NPG; ++n) {
            float w = sc[t][n];
            float4 v = *(const float4*)(xg + (size_t)n * HDIM + c4 * 4);
            acc.x += w * v.x; acc.y += w * v.y; acc.z += w * v.z; acc.w += w * v.w;
        }
        *(float4*)&rr[t][c4 * 4] = acc;
    }
    __syncthreads();
    {
        int t = tid >> 5, d = tid & 31;
        float acc = qkv_b[256 + h * 32 + d];
        for (int c = 0; c < 128; ++c)
            acc += rr[t][c] * qkv_w[c * 384 + 256 + h * 32 + d];
        O[((size_t)b * TTOK + t) * HDIM + h * 32 + d] = acc;
    }
}

// ================= mamba: one block per graph; GF[b][:] = mean_t output =================
__global__ __launch_bounds__(256) void mamba_kernel(const float* __restrict__ TOKp,
    const float* __restrict__ in_w, const float* __restrict__ conv_w,
    const float* __restrict__ conv_b, const float* __restrict__ x_w,
    const float* __restrict__ dt_w, const float* __restrict__ dt_b,
    const float* __restrict__ A_log, const float* __restrict__ Dp,
    const float* __restrict__ out_w, const float* __restrict__ norm_w,
    const float* __restrict__ normf_w, float* __restrict__ GF)
{
    constexpr int I = 256, S = 16;
    __shared__ float tok[TTOK][HDIM];
    __shared__ float hn[TTOK][HDIM];
    __shared__ float uu[TTOK][I];
    __shared__ float gg[TTOK][I];
    __shared__ float dtl[TTOK][I];
    __shared__ float ssm[TTOK][40];
    __shared__ float yy[TTOK][I];
    int b = blockIdx.x, tid = threadIdx.x;
    for (int i = tid; i < TTOK * HDIM; i += 256) tok[i >> 7][i & 127] = TOKp[(size_t)b * TTOK * HDIM + i];
    __syncthreads();
    {
        int t = tid >> 5, lane = tid & 31;
        float s = 0.f;
        for (int c = lane; c < HDIM; c += 32) { float v = tok[t][c]; s += v * v; }
        for (int off = 16; off; off >>= 1) s += __shfl_down(s, off, 32);
        s = __shfl(s, 0, 32);
        float r = rsqrtf(s / HDIM + 1e-5f);
        for (int c = lane; c < HDIM; c += 32) hn[t][c] = tok[t][c] * r * norm_w[c];
    }
    __syncthreads();
    for (int it = 0; it < 16; ++it) {
        int idx = it * 256 + tid;
        int t = idx >> 9, j = idx & 511;
        float acc = 0.f;
        for (int c = 0; c < 128; ++c) acc += hn[t][c] * in_w[c * 512 + j];
        if (j < 256) uu[t][j] = acc; else gg[t][j - 256] = acc;
    }
    __syncthreads();
    {
        int i = tid;
        float cw0 = conv_w[i * 4 + 0], cw1 = conv_w[i * 4 + 1];
        float cw2 = conv_w[i * 4 + 2], cw3 = conv_w[i * 4 + 3];
        float cb = conv_b[i];
        float uv[TTOK];
        for (int t = 0; t < TTOK; ++t) uv[t] = uu[t][i];
        for (int t = 0; t < TTOK; ++t) {
            float a = cw3 * uv[t] + cb;
            if (t >= 1) a += cw2 * uv[t - 1];
            if (t >= 2) a += cw1 * uv[t - 2];
            if (t >= 3) a += cw0 * uv[t - 3];
            float sg = 1.f / (1.f + __expf(-a));
            uu[t][i] = a * sg;
        }
    }
    __syncthreads();
    for (int idx = tid; idx < TTOK * 40; idx += 256) {
        int t = idx / 40, j = idx % 40;
        float acc = 0.f;
        for (int c = 0; c < 256; ++c) acc += uu[t][c] * x_w[c * 40 + j];
        ssm[t][j] = acc;
    }
    __syncthreads();
    for (int idx = tid; idx < TTOK * I; idx += 256) {
        int t = idx >> 8, i = idx & 255;
        float acc = dt_b[i];
        for (int r = 0; r < 8; ++r) acc += ssm[t][r] * dt_w[r * 256 + i];
        dtl[t][i] = (acc > 20.f) ? acc : log1pf(__expf(acc));
    }
    __syncthreads();
    {
        int i = tid;
        float a[S], st[S];
        for (int s = 0; s < S; ++s) { a[s] = -__expf(A_log[i * S + s]); st[s] = 0.f; }
        float Di = Dp[i];
        for (int t = 0; t < TTOK; ++t) {
            float d = dtl[t][i];
            float ut = uu[t][i];
            float y = 0.f;
            for (int s = 0; s < S; ++s) {
                float dA = __expf(d * a[s]);
                st[s] = dA * st[s] + d * ssm[t][8 + s] * ut;
                y += st[s] * ssm[t][24 + s];
            }
            y += ut * Di;
            float g = gg[t][i];
            float sg = 1.f / (1.f + __expf(-g));
            yy[t][i] = y * g * sg;
        }
    }
    __syncthreads();
    for (int idx = tid; idx < TTOK * HDIM; idx += 256) {
        int t = idx >> 7, c = idx & 127;
        float acc = tok[t][c];
        for (int i = 0; i < 256; ++i) acc += yy[t][i] * out_w[i * 128 + c];
        hn[t][c] = acc;
    }
    __syncthreads();
    {
        int t = tid >> 5, lane = tid & 31;
        float s = 0.f;
        for (int c = lane; c < HDIM; c += 32) { float v = hn[t][c]; s += v * v; }
        for (int off = 16; off; off >>= 1) s += __shfl_down(s, off, 32);
        s = __shfl(s, 0, 32);
        float r = rsqrtf(s / HDIM + 1e-5f);
        for (int c = lane; c < HDIM; c += 32) hn[t][c] = hn[t][c] * r * normf_w[c];
    }
    __syncthreads();
    for (int c = tid; c < HDIM; c += 256) {
        float s = 0.f;
        for (int t = 0; t < TTOK; ++t) s += hn[t][c];
        GF[(size_t)b * HDIM + c] = s * (1.f / TTOK);
    }
}

// ================= final GIN + segment_sum: partial sums, 32 blocks/graph =================
__global__ __launch_bounds__(256) void final_partial_kernel(const float* __restrict__ X,
    const int* __restrict__ ssrc, const int* __restrict__ starts,
    float* __restrict__ PS)
{
    __shared__ float part[8][HDIM];
    int b = blockIdx.x >> 5;        // graph
    int j = blockIdx.x & 31;        // slice within graph
    int tid = threadIdx.x;
    int g = tid >> 5, lane = tid & 31;
    const int c = lane * 4;
    float4 acc = {0.f, 0.f, 0.f, 0.f};
    // self rows: this block covers nodes [j*32, (j+1)*32)
    {
        int nb = j * 32 + g * 4;
        for (int n = nb; n < nb + 4; ++n) {
            float4 v = *(const float4*)(X + ((size_t)b * NPG + n) * HDIM + c);
            acc.x += v.x; acc.y += v.y; acc.z += v.z; acc.w += v.w;
        }
    }
    // edge rows: contiguous chunk of this graph's dst-sorted edge list
    {
        int e0 = starts[b * NPG], e1 = starts[(b + 1) * NPG];
        int tot = e1 - e0;
        int gi = j * 8 + g;                      // 0..255
        int per = (tot + 255) >> 8;
        int cs = e0 + gi * per;
        int ce = min(cs + per, e1);
        for (int j0 = cs; j0 < ce; j0 += 32) {
            int myid = (j0 + lane < ce) ? ssrc[j0 + lane] : 0;
            int m = min(32, ce - j0);
            for (int jj = 0; jj < m; ++jj) {
                int sa = __shfl(myid, jj, 32);
                float4 va = *(const float4*)(X + (size_t)sa * HDIM + c);
                acc.x += va.x; acc.y += va.y; acc.z += va.z; acc.w += va.w;
            }
        }
    }
    *(float4*)&part[g][c] = acc;
    __syncthreads();
    if (tid < HDIM) {
        float s = 0.f;
        for (int gg = 0; gg < 8; ++gg) s += part[gg][tid];
        atomicAdd(&PS[(size_t)b * HDIM + tid], s);
    }
}

__global__ __launch_bounds__(128) void final_mm_kernel(const float* __restrict__ PS,
    const float* __restrict__ w_out, const float* __restrict__ b_out,
    float* __restrict__ out)
{
    __shared__ float Sm[HDIM];
    int b = blockIdx.x, tid = threadIdx.x;
    Sm[tid] = PS[(size_t)b * HDIM + tid];
    __syncthreads();
    float acc = 1024.f * b_out[tid];
    for (int k = 0; k < 128; ++k) acc += Sm[k] * w_out[k * 128 + tid];
    out[(size_t)b * HDIM + tid] = acc;
}

extern "C" void kernel_launch(void* const* d_in, const int* in_sizes, int n_in,
                              void* d_out, int out_size, void* d_ws, size_t ws_size,
                              hipStream_t stream)
{
    const int N = in_sizes[0] / HDIM;      // 131072
    const int E = in_sizes[1] / 2;         // 2097152
    const int B = N >> 10;                 // 128 graphs

    const float* x_in  = (const float*)d_in[0];
    const int*   src   = (const int*)d_in[1];
    const int*   dst   = src + E;
    const float* w_in  = (const float*)d_in[5];
    const float* b_in  = (const float*)d_in[6];
    const float* gin_w = (const float*)d_in[7];
    const float* gin_b = (const float*)d_in[8];
    const float* vt    = (const float*)d_in[9];
    const float* qkv_w = (const float*)d_in[10];
    const float* qkv_b = (const float*)d_in[11];
    const float* ao_w  = (const float*)d_in[12];
    const float* ao_b  = (const float*)d_in[13];
    const float* m_in_w   = (const float*)d_in[14];
    const float* m_conv_w = (const float*)d_in[15];
    const float* m_conv_b = (const float*)d_in[16];
    const float* m_x_w    = (const float*)d_in[17];
    const float* m_dt_w   = (const float*)d_in[18];
    const float* m_dt_b   = (const float*)d_in[19];
    const float* m_A_log  = (const float*)d_in[20];
    const float* m_D      = (const float*)d_in[21];
    const float* m_out_w  = (const float*)d_in[22];
    const float* m_norm_w = (const float*)d_in[23];
    const float* m_normf_w= (const float*)d_in[24];
    const float* w_out = (const float*)d_in[25];
    const float* b_out = (const float*)d_in[26];
    float* out = (float*)d_out;

    float* X   = (float*)d_ws;                    // N*128
    float* A   = X + (size_t)N * HDIM;            // N*128
    float* TOK = A + (size_t)N * HDIM;            // B*8*128
    float* O   = TOK + (size_t)B * TTOK * HDIM;   // B*8*128
    float* GF  = O + (size_t)B * TTOK * HDIM;     // B*128
    float* P   = GF + (size_t)B * HDIM;           // 4*8*128
    float* PS  = P + 4 * TTOK * HDIM;             // B*128
    int* count    = (int*)(PS + (size_t)B * HDIM);// N
    int* starts   = count + N;                    // N+1
    int* cursor   = starts + N + 1;               // N
    int* blocksum = cursor + N;                   // 512
    int* blockoff = blocksum + 512;               // 512
    int* ssrc     = blockoff + 512;               // E

    const int EB = (E + 255) / 256;   // 8192
    const int NB = N / 256;           // 512

    // ---- counting sort of edges by dst (once, reused by all 4 GINs) ----
    hipMemsetAsync(count, 0, (size_t)N * sizeof(int), stream);
    hist_kernel<<<EB, 256, 0, stream>>>(dst, count, E);
    reduce256_kernel<<<NB, 256, 0, stream>>>(count, blocksum);
    scan512_kernel<<<1, 512, 0, stream>>>(blocksum, blockoff);
    scan_local_kernel<<<NB, 256, 0, stream>>>(count, blockoff, starts, cursor, N);
    sort_scatter_kernel<<<EB, 256, 0, stream>>>(src, dst, cursor, ssrc, E);

    // ---- input GIN: X = (x + agg(x)) @ w_in + b_in ----
    gather_kernel<<<N / 8, 256, 0, stream>>>(x_in, ssrc, starts, count, A);
    lin128_kernel<<<N / 32, 256, 0, stream>>>(A, w_in, b_in, nullptr, X);

    for (int l = 0; l < 2; ++l) {
        // gather on current X (GIN agg), attention on current X
        gather_kernel<<<N / 8, 256, 0, stream>>>(X, ssrc, starts, count, A);
        attn_prep_kernel<<<1, 256, 0, stream>>>(vt + (size_t)l * TTOK * HDIM,
                                                qkv_w + (size_t)l * 128 * 384,
                                                qkv_b + (size_t)l * 384, P);
        attn_main_kernel<<<B * 4, 256, 0, stream>>>(X, P,
                                                    qkv_w + (size_t)l * 128 * 384,
                                                    qkv_b + (size_t)l * 384, O);
        lin128_kernel<<<(B * TTOK) / 32, 256, 0, stream>>>(O, ao_w + (size_t)l * 128 * 128,
                                                           ao_b + (size_t)l * 128, nullptr, TOK);
        mamba_kernel<<<B, 256, 0, stream>>>(TOK, m_in_w, m_conv_w, m_conv_b, m_x_w,
                                            m_dt_w, m_dt_b, m_A_log, m_D, m_out_w,
                                            m_norm_w, m_normf_w, GF);
        // X_new = (A @ gin_w + gin_b) + GF[batch]   (fused epilogue)
        lin128_kernel<<<N / 32, 256, 0, stream>>>(A, gin_w + (size_t)l * 128 * 128,
                                                  gin_b + (size_t)l * 128, GF, X);
    }

    // ---- final GIN + segment_sum: partials + tiny matmul ----
    hipMemsetAsync(PS, 0, (size_t)B * HDIM * sizeof(float), stream);
    final_partial_kernel<<<B * 32, 256, 0, stream>>>(X, ssrc, starts, PS);
    final_mm_kernel<<<B, 128, 0, stream>>>(PS, w_out, b_out, out);

    (void)n_in; (void)out_size; (void)ws_size;
}